// Round 1
// baseline (204.148 us; speedup 1.0000x reference)
//
#include <hip/hip_runtime.h>
#include <hip/hip_bf16.h>

#define N_NODES 8192
#define N_EDGES 16384
#define IN_CH 32
#define HID 64
#define OUT_CH 2
#define EDGE_DIM 4
#define N_LAYERS 3
#define N_GRAPHS 256
#define BN_EPS 1e-5f
#define YCOLS 320   // 4*64 (edge_W columns) + 64 (edge_b column block)

// h[n][c] = sum_k x[n][k] * W[k][c] + b[c]
__global__ void lin_in_kernel(const float* __restrict__ x,
                              const float* __restrict__ W,
                              const float* __restrict__ b,
                              float* __restrict__ h) {
    int idx = blockIdx.x * blockDim.x + threadIdx.x;   // node*64 + col
    int n = idx >> 6, c = idx & 63;
    const float* xr = x + n * IN_CH;
    float acc = b[c];
#pragma unroll
    for (int k = 0; k < IN_CH; ++k) acc += xr[k] * W[k * HID + c];
    h[idx] = acc;
}

// y[n][d*64+o] = sum_k h[n][k] * edge_W_l[d][k*64+o]   (d = 0..3)
// y[n][256+o]  = sum_k h[n][k] * edge_b_l[k*64+o]
// blockDim = 320 (one thread per output column), 32 nodes per block.
__global__ void ynet_kernel(const float* __restrict__ h,
                            const float* __restrict__ edge_W_l,   // [4,4096]
                            const float* __restrict__ edge_b_l,   // [4096]
                            float* __restrict__ y) {
    __shared__ float hs[32 * HID];
    int t = threadIdx.x;               // 0..319
    int node0 = blockIdx.x * 32;

    // Load this thread's weight column into registers (64 VGPRs).
    float w[64];
    if (t < 256) {
        int d = t >> 6, o = t & 63;
        const float* base = edge_W_l + d * (HID * HID) + o;
#pragma unroll
        for (int k = 0; k < HID; ++k) w[k] = base[k * HID];
    } else {
        int o = t & 63;
        const float* base = edge_b_l + o;
#pragma unroll
        for (int k = 0; k < HID; ++k) w[k] = base[k * HID];
    }

    for (int i = t; i < 32 * HID; i += 320) hs[i] = h[node0 * HID + i];
    __syncthreads();

    for (int nn = 0; nn < 32; ++nn) {
        float acc = 0.f;
        const float* hr = hs + nn * HID;
#pragma unroll
        for (int k = 0; k < HID; ++k) acc += hr[k] * w[k];   // LDS broadcast
        y[(size_t)(node0 + nn) * YCOLS + t] = acc;
    }
}

// One wave per edge: msg = sum_d ea[d]*y[src][d*64+lane] + y[src][256+lane]
// then atomic scatter into agg[dst].
__global__ void edge_kernel(const float* __restrict__ y,
                            const float* __restrict__ edge_attr,
                            const int* __restrict__ edge_index,
                            float* __restrict__ agg) {
    int e = blockIdx.x * 4 + (threadIdx.x >> 6);
    int lane = threadIdx.x & 63;
    if (e >= N_EDGES) return;
    int src = edge_index[e];
    int dst = edge_index[N_EDGES + e];
    float a0 = edge_attr[e * 4 + 0];
    float a1 = edge_attr[e * 4 + 1];
    float a2 = edge_attr[e * 4 + 2];
    float a3 = edge_attr[e * 4 + 3];
    const float* yr = y + (size_t)src * YCOLS;
    float m = a0 * yr[lane] + a1 * yr[64 + lane] + a2 * yr[128 + lane] +
              a3 * yr[192 + lane] + yr[256 + lane];
    atomicAdd(&agg[dst * HID + lane], m);
}

// h_out = relu(bn(agg + h @ root_W + conv_b))
// blockDim 256, 16 nodes per block (each thread: 4 nodes, fixed col).
__global__ void update_kernel(const float* __restrict__ h,
                              const float* __restrict__ agg,
                              const float* __restrict__ root_W_l,   // [64,64]
                              const float* __restrict__ conv_b_l,
                              const float* __restrict__ bn_gamma_l,
                              const float* __restrict__ bn_beta_l,
                              const float* __restrict__ bn_mean_l,
                              const float* __restrict__ bn_var_l,
                              float* __restrict__ h_out) {
    __shared__ float Ws[HID * HID];   // 16 KB
    __shared__ float hs[16 * HID];    // 4 KB
    int t = threadIdx.x;
    int node0 = blockIdx.x * 16;
    for (int i = t; i < HID * HID; i += 256) Ws[i] = root_W_l[i];
    for (int i = t; i < 16 * HID; i += 256) hs[i] = h[node0 * HID + i];
    __syncthreads();

    int col = t & 63;
    int grp = t >> 6;   // 0..3
    float scale = bn_gamma_l[col] * rsqrtf(bn_var_l[col] + BN_EPS);
    float shift = bn_beta_l[col] - bn_mean_l[col] * scale;
    float cb = conv_b_l[col];
#pragma unroll
    for (int g = 0; g < 4; ++g) {
        int nn = grp * 4 + g;
        float acc = 0.f;
        const float* hr = hs + nn * HID;
#pragma unroll
        for (int k = 0; k < HID; ++k) acc += hr[k] * Ws[k * HID + col];
        int node = node0 + nn;
        float v = agg[node * HID + col] + acc + cb;
        v = v * scale + shift;          // BN (inference)
        v = fmaxf(v, 0.f);              // ReLU
        h_out[node * HID + col] = v;
    }
}

__global__ void pool_kernel(const float* __restrict__ h,
                            const int* __restrict__ batch,
                            float* __restrict__ pooled) {
    int idx = blockIdx.x * blockDim.x + threadIdx.x;  // node*64+col
    int node = idx >> 6, col = idx & 63;
    atomicAdd(&pooled[batch[node] * HID + col], h[idx]);
}

__global__ void clf_kernel(const float* __restrict__ pooled,
                           const float* __restrict__ W,   // [64,2]
                           const float* __restrict__ b,
                           float* __restrict__ out) {
    int g = threadIdx.x;   // 0..255, one thread per graph
    float acc0 = b[0], acc1 = b[1];
    const float* pr = pooled + g * HID;
#pragma unroll
    for (int k = 0; k < HID; ++k) {
        float p = pr[k];
        acc0 += p * W[k * 2 + 0];
        acc1 += p * W[k * 2 + 1];
    }
    out[g * 2 + 0] = acc0;
    out[g * 2 + 1] = acc1;
}

extern "C" void kernel_launch(void* const* d_in, const int* in_sizes, int n_in,
                              void* d_out, int out_size, void* d_ws, size_t ws_size,
                              hipStream_t stream) {
    const float* x         = (const float*)d_in[0];
    const int*   edge_index= (const int*)  d_in[1];
    const float* edge_attr = (const float*)d_in[2];
    const int*   batch     = (const int*)  d_in[3];
    const float* lin_in_W  = (const float*)d_in[4];
    const float* lin_in_b  = (const float*)d_in[5];
    const float* edge_W    = (const float*)d_in[6];   // [3,4,4096]
    const float* edge_b    = (const float*)d_in[7];   // [3,4096]
    const float* root_W    = (const float*)d_in[8];   // [3,64,64]
    const float* conv_b    = (const float*)d_in[9];   // [3,64]
    const float* bn_gamma  = (const float*)d_in[10];
    const float* bn_beta   = (const float*)d_in[11];
    const float* bn_mean   = (const float*)d_in[12];
    const float* bn_var    = (const float*)d_in[13];
    const float* clf_W     = (const float*)d_in[14];
    const float* clf_b     = (const float*)d_in[15];
    float* out = (float*)d_out;

    char* ws = (char*)d_ws;
    float* hA     = (float*)(ws);                                  // 2 MB
    float* hB     = (float*)(ws + (size_t)2 * 1024 * 1024);        // 2 MB
    float* y      = (float*)(ws + (size_t)4 * 1024 * 1024);        // 10 MB
    float* agg    = (float*)(ws + (size_t)14 * 1024 * 1024);       // 2 MB
    float* pooled = (float*)(ws + (size_t)16 * 1024 * 1024);       // 64 KB

    // lin_in
    lin_in_kernel<<<N_NODES * HID / 256, 256, 0, stream>>>(x, lin_in_W, lin_in_b, hA);

    float* h_cur = hA;
    float* h_nxt = hB;
    for (int l = 0; l < N_LAYERS; ++l) {
        ynet_kernel<<<N_NODES / 32, 320, 0, stream>>>(
            h_cur, edge_W + (size_t)l * EDGE_DIM * HID * HID,
            edge_b + (size_t)l * HID * HID, y);
        hipMemsetAsync(agg, 0, (size_t)N_NODES * HID * sizeof(float), stream);
        edge_kernel<<<N_EDGES / 4, 256, 0, stream>>>(y, edge_attr, edge_index, agg);
        update_kernel<<<N_NODES / 16, 256, 0, stream>>>(
            h_cur, agg, root_W + (size_t)l * HID * HID, conv_b + (size_t)l * HID,
            bn_gamma + (size_t)l * HID, bn_beta + (size_t)l * HID,
            bn_mean + (size_t)l * HID, bn_var + (size_t)l * HID, h_nxt);
        float* tmp = h_cur; h_cur = h_nxt; h_nxt = tmp;
    }

    hipMemsetAsync(pooled, 0, (size_t)N_GRAPHS * HID * sizeof(float), stream);
    pool_kernel<<<N_NODES * HID / 256, 256, 0, stream>>>(h_cur, batch, pooled);
    clf_kernel<<<1, 256, 0, stream>>>(pooled, clf_W, clf_b, out);
}

// Round 2
// 116.537 us; speedup vs baseline: 1.7518x; 1.7518x over previous
//
#include <hip/hip_runtime.h>
#include <hip/hip_bf16.h>

#define N_NODES 8192
#define N_EDGES 16384
#define IN_CH 32
#define HID 64
#define OUT_CH 2
#define EDGE_DIM 4
#define N_LAYERS 3
#define N_GRAPHS 256
#define BN_EPS 1e-5f
#define YCOLS 320   // 4*64 (edge_W col-tiles) + 64 (edge_b col-tile)

// h[n][c] = sum_k x[n][k] * W[k][c] + b[c]
__global__ void lin_in_kernel(const float* __restrict__ x,
                              const float* __restrict__ W,
                              const float* __restrict__ b,
                              float* __restrict__ h) {
    int idx = blockIdx.x * blockDim.x + threadIdx.x;   // node*64 + col
    int n = idx >> 6, c = idx & 63;
    const float* xr = x + n * IN_CH;
    float acc = b[c];
#pragma unroll
    for (int k = 0; k < IN_CH; ++k) acc += xr[k] * W[k * HID + c];
    h[idx] = acc;
}

// y = h @ [W_0 | W_1 | W_2 | W_3 | B]  ([8192,64] @ [64,320])
// Tiled: block = 256 threads -> 16 nodes x 64 cols. grid = (512, 5).
// Each thread: 4 outputs (4 nodes, fixed col) -> ILP 4.
__global__ __launch_bounds__(256) void ynet_kernel(
        const float* __restrict__ h,
        const float* __restrict__ edge_W_l,   // [4,64*64] = [d][k*64+o]
        const float* __restrict__ edge_b_l,   // [64*64]   = [k*64+o]
        float* __restrict__ y) {
    __shared__ float Ws[HID * 64];    // [k][c]  16 KB
    __shared__ float hs[16 * HID];    //          4 KB
    int t = threadIdx.x;
    int node0 = blockIdx.x * 16;
    int ct = blockIdx.y;              // col tile 0..4
    const float* wsrc = (ct < 4) ? (edge_W_l + (size_t)ct * HID * HID) : edge_b_l;
    for (int i = t; i < HID * 64; i += 256) Ws[i] = wsrc[i];
    for (int i = t; i < 16 * HID; i += 256) hs[i] = h[node0 * HID + i];
    __syncthreads();

    int c = t & 63, g = t >> 6;       // wave-uniform g
    const float* h0 = hs + (g * 4 + 0) * HID;
    const float* h1 = hs + (g * 4 + 1) * HID;
    const float* h2 = hs + (g * 4 + 2) * HID;
    const float* h3 = hs + (g * 4 + 3) * HID;
    float acc0 = 0.f, acc1 = 0.f, acc2 = 0.f, acc3 = 0.f;
#pragma unroll
    for (int k = 0; k < HID; ++k) {
        float wk = Ws[k * 64 + c];    // stride-1 across lanes, conflict-free
        acc0 += h0[k] * wk;           // wave-uniform addr -> broadcast
        acc1 += h1[k] * wk;
        acc2 += h2[k] * wk;
        acc3 += h3[k] * wk;
    }
    size_t colbase = (size_t)ct * 64 + c;
    y[(size_t)(node0 + g * 4 + 0) * YCOLS + colbase] = acc0;
    y[(size_t)(node0 + g * 4 + 1) * YCOLS + colbase] = acc1;
    y[(size_t)(node0 + g * 4 + 2) * YCOLS + colbase] = acc2;
    y[(size_t)(node0 + g * 4 + 3) * YCOLS + colbase] = acc3;
}

// One wave per edge: msg = sum_d ea[d]*y[src][d*64+lane] + y[src][256+lane]
// then atomic scatter into agg[dst].
__global__ __launch_bounds__(256) void edge_kernel(
        const float* __restrict__ y,
        const float* __restrict__ edge_attr,
        const int* __restrict__ edge_index,
        float* __restrict__ agg) {
    int e = blockIdx.x * 4 + (threadIdx.x >> 6);
    int lane = threadIdx.x & 63;
    int src = edge_index[e];
    int dst = edge_index[N_EDGES + e];
    float4 a = *(const float4*)(edge_attr + (size_t)e * 4);
    const float* yr = y + (size_t)src * YCOLS;
    float m = a.x * yr[lane] + a.y * yr[64 + lane] + a.z * yr[128 + lane] +
              a.w * yr[192 + lane] + yr[256 + lane];
    atomicAdd(&agg[dst * HID + lane], m);
}

// h_out = relu(bn(agg + h @ root_W + conv_b)); zeroes agg in place.
// If DO_POOL, atomically accumulates into pooled instead of writing h_out.
template <int DO_POOL>
__global__ __launch_bounds__(256) void update_kernel(
        const float* __restrict__ h,
        float* __restrict__ agg,
        const float* __restrict__ root_W_l,   // [64,64]
        const float* __restrict__ conv_b_l,
        const float* __restrict__ bn_gamma_l,
        const float* __restrict__ bn_beta_l,
        const float* __restrict__ bn_mean_l,
        const float* __restrict__ bn_var_l,
        const int* __restrict__ batch,
        float* __restrict__ pooled,
        float* __restrict__ h_out) {
    __shared__ float Ws[HID * HID];   // 16 KB
    __shared__ float hs[16 * HID];    //  4 KB
    int t = threadIdx.x;
    int node0 = blockIdx.x * 16;
    for (int i = t; i < HID * HID; i += 256) Ws[i] = root_W_l[i];
    for (int i = t; i < 16 * HID; i += 256) hs[i] = h[node0 * HID + i];
    __syncthreads();

    int col = t & 63;
    int grp = t >> 6;   // 0..3
    float scale = bn_gamma_l[col] * rsqrtf(bn_var_l[col] + BN_EPS);
    float shift = bn_beta_l[col] - bn_mean_l[col] * scale;
    float cb = conv_b_l[col];
#pragma unroll
    for (int g = 0; g < 4; ++g) {
        int nn = grp * 4 + g;
        float acc = 0.f;
        const float* hr = hs + nn * HID;
#pragma unroll
        for (int k = 0; k < HID; ++k) acc += hr[k] * Ws[k * HID + col];
        int node = node0 + nn;
        float av = agg[node * HID + col];
        agg[node * HID + col] = 0.f;           // reset for next layer / replay
        float v = av + acc + cb;
        v = v * scale + shift;                  // BN (inference)
        v = fmaxf(v, 0.f);                      // ReLU
        if (DO_POOL) {
            atomicAdd(&pooled[batch[node] * HID + col], v);
        } else {
            h_out[node * HID + col] = v;
        }
    }
}

// One block: 256 threads, one graph each. Zeroes pooled after reading so the
// buffer returns to its zero state for the next graph replay.
__global__ void clf_kernel(float* __restrict__ pooled,
                           const float* __restrict__ W,   // [64,2]
                           const float* __restrict__ b,
                           float* __restrict__ out) {
    int g = threadIdx.x;   // 0..255
    float acc0 = b[0], acc1 = b[1];
    float* pr = pooled + g * HID;
#pragma unroll
    for (int k = 0; k < HID; ++k) {
        float p = pr[k];
        acc0 += p * W[k * 2 + 0];
        acc1 += p * W[k * 2 + 1];
    }
    out[g * 2 + 0] = acc0;
    out[g * 2 + 1] = acc1;
#pragma unroll
    for (int k = 0; k < HID; ++k) pr[k] = 0.f;
}

extern "C" void kernel_launch(void* const* d_in, const int* in_sizes, int n_in,
                              void* d_out, int out_size, void* d_ws, size_t ws_size,
                              hipStream_t stream) {
    const float* x         = (const float*)d_in[0];
    const int*   edge_index= (const int*)  d_in[1];
    const float* edge_attr = (const float*)d_in[2];
    const int*   batch     = (const int*)  d_in[3];
    const float* lin_in_W  = (const float*)d_in[4];
    const float* lin_in_b  = (const float*)d_in[5];
    const float* edge_W    = (const float*)d_in[6];   // [3,4,4096]
    const float* edge_b    = (const float*)d_in[7];   // [3,4096]
    const float* root_W    = (const float*)d_in[8];   // [3,64,64]
    const float* conv_b    = (const float*)d_in[9];   // [3,64]
    const float* bn_gamma  = (const float*)d_in[10];
    const float* bn_beta   = (const float*)d_in[11];
    const float* bn_mean   = (const float*)d_in[12];
    const float* bn_var    = (const float*)d_in[13];
    const float* clf_W     = (const float*)d_in[14];
    const float* clf_b     = (const float*)d_in[15];
    float* out = (float*)d_out;

    char* ws = (char*)d_ws;
    float* hA     = (float*)(ws);                                  // 2 MB
    float* hB     = (float*)(ws + (size_t)2 * 1024 * 1024);        // 2 MB
    float* agg    = (float*)(ws + (size_t)4 * 1024 * 1024);        // 2 MB
    float* pooled = (float*)(ws + (size_t)6 * 1024 * 1024);        // 64 KB
    float* y      = (float*)(ws + (size_t)8 * 1024 * 1024);        // 10.5 MB

    // One memset covers agg (2 MB) + pooled (64 KB): clears 0xAA poison on the
    // first call; subsequent calls it re-clears (kernels also self-restore).
    hipMemsetAsync(agg, 0, (size_t)2 * 1024 * 1024 + 64 * 1024, stream);

    lin_in_kernel<<<N_NODES * HID / 256, 256, 0, stream>>>(x, lin_in_W, lin_in_b, hA);

    float* h_cur = hA;
    float* h_nxt = hB;
    for (int l = 0; l < N_LAYERS; ++l) {
        dim3 ygrid(N_NODES / 16, 5);
        ynet_kernel<<<ygrid, 256, 0, stream>>>(
            h_cur, edge_W + (size_t)l * EDGE_DIM * HID * HID,
            edge_b + (size_t)l * HID * HID, y);
        edge_kernel<<<N_EDGES / 4, 256, 0, stream>>>(y, edge_attr, edge_index, agg);
        if (l < N_LAYERS - 1) {
            update_kernel<0><<<N_NODES / 16, 256, 0, stream>>>(
                h_cur, agg, root_W + (size_t)l * HID * HID, conv_b + (size_t)l * HID,
                bn_gamma + (size_t)l * HID, bn_beta + (size_t)l * HID,
                bn_mean + (size_t)l * HID, bn_var + (size_t)l * HID,
                batch, pooled, h_nxt);
        } else {
            update_kernel<1><<<N_NODES / 16, 256, 0, stream>>>(
                h_cur, agg, root_W + (size_t)l * HID * HID, conv_b + (size_t)l * HID,
                bn_gamma + (size_t)l * HID, bn_beta + (size_t)l * HID,
                bn_mean + (size_t)l * HID, bn_var + (size_t)l * HID,
                batch, pooled, h_nxt);
        }
        float* tmp = h_cur; h_cur = h_nxt; h_nxt = tmp;
    }

    clf_kernel<<<1, 256, 0, stream>>>(pooled, clf_W, clf_b, out);
}

// Round 3
// 89.856 us; speedup vs baseline: 2.2719x; 1.2969x over previous
//
#include <hip/hip_runtime.h>
#include <hip/hip_bf16.h>

#define N_NODES 8192
#define N_EDGES 16384
#define IN_CH 32
#define HID 64
#define OUT_CH 2
#define EDGE_DIM 4
#define N_LAYERS 3
#define N_GRAPHS 256
#define BN_EPS 1e-5f
#define NT 512     // threads per fused node-kernel block
#define NPB 32     // nodes per block -> grid 256

// ---- shared ynet phase: y4/yb = h @ [W0..W3 | B] for this block's 32 nodes.
// Thread (c = t&63, g = t>>6): 4 nodes x 5 outputs in registers.
// Weights streamed from global (same 80 KB for every block -> L1/L2-hot);
// h read from LDS as float4.
__device__ __forceinline__ void ynet_phase(const float* __restrict__ hs,
                                           const float* __restrict__ eW,  // [4,4096]
                                           const float* __restrict__ eB,  // [4096]
                                           float4* __restrict__ y4,
                                           float* __restrict__ yb,
                                           int node0, int c, int g) {
    float acc[4][5];
#pragma unroll
    for (int j = 0; j < 4; ++j)
#pragma unroll
        for (int d = 0; d < 5; ++d) acc[j][d] = 0.f;

    const float4* h0v = (const float4*)(hs + (g * 4 + 0) * HID);
    const float4* h1v = (const float4*)(hs + (g * 4 + 1) * HID);
    const float4* h2v = (const float4*)(hs + (g * 4 + 2) * HID);
    const float4* h3v = (const float4*)(hs + (g * 4 + 3) * HID);

#pragma unroll 2
    for (int k4 = 0; k4 < HID / 4; ++k4) {
        float4 hv[4];
        hv[0] = h0v[k4]; hv[1] = h1v[k4]; hv[2] = h2v[k4]; hv[3] = h3v[k4];
        const float* hf = (const float*)hv;
#pragma unroll
        for (int kk = 0; kk < 4; ++kk) {
            int k = k4 * 4 + kk;
            float w0 = eW[0 * 4096 + k * 64 + c];
            float w1 = eW[1 * 4096 + k * 64 + c];
            float w2 = eW[2 * 4096 + k * 64 + c];
            float w3 = eW[3 * 4096 + k * 64 + c];
            float w4 = eB[k * 64 + c];
#pragma unroll
            for (int j = 0; j < 4; ++j) {
                float hk = hf[j * 4 + kk];
                acc[j][0] += hk * w0;
                acc[j][1] += hk * w1;
                acc[j][2] += hk * w2;
                acc[j][3] += hk * w3;
                acc[j][4] += hk * w4;
            }
        }
    }
#pragma unroll
    for (int j = 0; j < 4; ++j) {
        int n = node0 + g * 4 + j;
        y4[n * HID + c] = make_float4(acc[j][0], acc[j][1], acc[j][2], acc[j][3]);
        yb[n * HID + c] = acc[j][4];
    }
}

// K0: zero agg+pooled, h = x@Win+b (to LDS + global), then ynet layer 0.
__global__ __launch_bounds__(NT) void k0_fused(
        const float* __restrict__ x,
        const float* __restrict__ Win, const float* __restrict__ bin,
        const float* __restrict__ eW0, const float* __restrict__ eB0,
        float* __restrict__ hA, float4* __restrict__ y4, float* __restrict__ yb,
        float* __restrict__ agg, float* __restrict__ pooled) {
    __shared__ float Wis[IN_CH * HID];   // 8 KB
    __shared__ float xs[NPB * IN_CH];    // 4 KB
    __shared__ float hs[NPB * HID];      // 8 KB
    int t = threadIdx.x;
    int node0 = blockIdx.x * NPB;

    for (int i = t; i < NPB * HID; i += NT) agg[node0 * HID + i] = 0.f;
    if (t < 64) pooled[blockIdx.x * 64 + t] = 0.f;   // 256 blocks x 64 = 16384
    for (int i = t; i < IN_CH * HID; i += NT) Wis[i] = Win[i];
    for (int i = t; i < NPB * IN_CH; i += NT) xs[i] = x[node0 * IN_CH + i];
    __syncthreads();

    int c = t & 63, g = t >> 6;
    float b = bin[c];
    float a0 = b, a1 = b, a2 = b, a3 = b;
    const float* x0 = xs + (g * 4 + 0) * IN_CH;
    const float* x1 = xs + (g * 4 + 1) * IN_CH;
    const float* x2 = xs + (g * 4 + 2) * IN_CH;
    const float* x3 = xs + (g * 4 + 3) * IN_CH;
#pragma unroll
    for (int k = 0; k < IN_CH; ++k) {
        float wk = Wis[k * HID + c];
        a0 += x0[k] * wk; a1 += x1[k] * wk; a2 += x2[k] * wk; a3 += x3[k] * wk;
    }
    hs[(g * 4 + 0) * HID + c] = a0; hA[(node0 + g * 4 + 0) * HID + c] = a0;
    hs[(g * 4 + 1) * HID + c] = a1; hA[(node0 + g * 4 + 1) * HID + c] = a1;
    hs[(g * 4 + 2) * HID + c] = a2; hA[(node0 + g * 4 + 2) * HID + c] = a2;
    hs[(g * 4 + 3) * HID + c] = a3; hA[(node0 + g * 4 + 3) * HID + c] = a3;
    __syncthreads();

    ynet_phase(hs, eW0, eB0, y4, yb, node0, c, g);
}

// edge: m = dot(edge_attr[e], y4[src]) + yb[src]; atomic scatter to agg[dst].
__global__ __launch_bounds__(256) void edge_kernel(
        const float4* __restrict__ y4, const float* __restrict__ yb,
        const float* __restrict__ edge_attr, const int* __restrict__ edge_index,
        float* __restrict__ agg) {
    int e = blockIdx.x * 4 + (threadIdx.x >> 6);
    int lane = threadIdx.x & 63;
    int src = edge_index[e];
    int dst = edge_index[N_EDGES + e];
    float4 a = *(const float4*)(edge_attr + (size_t)e * 4);
    float4 yv = y4[(size_t)src * HID + lane];
    float m = a.x * yv.x + a.y * yv.y + a.z * yv.z + a.w * yv.w +
              yb[(size_t)src * HID + lane];
    atomicAdd(&agg[dst * HID + lane], m);
}

// update (l<2): h_new = relu(bn(agg + h@rootW + cb)); zero agg; store h_new;
// then ynet with NEXT layer's weights.
__global__ __launch_bounds__(NT) void k_upd_ynet(
        const float* __restrict__ h_in, float* __restrict__ agg,
        const float* __restrict__ rootW, const float* __restrict__ conv_b,
        const float* __restrict__ gam, const float* __restrict__ bet,
        const float* __restrict__ mu, const float* __restrict__ var,
        const float* __restrict__ eW_next, const float* __restrict__ eB_next,
        float* __restrict__ h_out, float4* __restrict__ y4, float* __restrict__ yb) {
    __shared__ float Ws[HID * HID];    // 16 KB
    __shared__ float hsin[NPB * HID];  // 8 KB
    __shared__ float hs[NPB * HID];    // 8 KB
    int t = threadIdx.x;
    int node0 = blockIdx.x * NPB;
    for (int i = t; i < HID * HID; i += NT) Ws[i] = rootW[i];
    for (int i = t; i < NPB * HID; i += NT) hsin[i] = h_in[node0 * HID + i];
    __syncthreads();

    int c = t & 63, g = t >> 6;
    float scale = gam[c] * rsqrtf(var[c] + BN_EPS);
    float shift = bet[c] - mu[c] * scale;
    float cb = conv_b[c];

    float acc[4] = {0.f, 0.f, 0.f, 0.f};
    const float4* h0v = (const float4*)(hsin + (g * 4 + 0) * HID);
    const float4* h1v = (const float4*)(hsin + (g * 4 + 1) * HID);
    const float4* h2v = (const float4*)(hsin + (g * 4 + 2) * HID);
    const float4* h3v = (const float4*)(hsin + (g * 4 + 3) * HID);
#pragma unroll 4
    for (int k4 = 0; k4 < HID / 4; ++k4) {
        float4 hv[4];
        hv[0] = h0v[k4]; hv[1] = h1v[k4]; hv[2] = h2v[k4]; hv[3] = h3v[k4];
        const float* hf = (const float*)hv;
#pragma unroll
        for (int kk = 0; kk < 4; ++kk) {
            float wk = Ws[(k4 * 4 + kk) * 64 + c];
#pragma unroll
            for (int j = 0; j < 4; ++j) acc[j] += hf[j * 4 + kk] * wk;
        }
    }
#pragma unroll
    for (int j = 0; j < 4; ++j) {
        int node = node0 + g * 4 + j;
        float av = agg[node * HID + c];
        agg[node * HID + c] = 0.f;
        float v = fmaxf((av + acc[j] + cb) * scale + shift, 0.f);
        hs[(g * 4 + j) * HID + c] = v;
        h_out[node * HID + c] = v;
    }
    __syncthreads();

    ynet_phase(hs, eW_next, eB_next, y4, yb, node0, c, g);
}

// last update: same math, but atomic-pool instead of storing h.
__global__ __launch_bounds__(NT) void k_upd_pool(
        const float* __restrict__ h_in, float* __restrict__ agg,
        const float* __restrict__ rootW, const float* __restrict__ conv_b,
        const float* __restrict__ gam, const float* __restrict__ bet,
        const float* __restrict__ mu, const float* __restrict__ var,
        const int* __restrict__ batch, float* __restrict__ pooled) {
    __shared__ float Ws[HID * HID];
    __shared__ float hsin[NPB * HID];
    int t = threadIdx.x;
    int node0 = blockIdx.x * NPB;
    for (int i = t; i < HID * HID; i += NT) Ws[i] = rootW[i];
    for (int i = t; i < NPB * HID; i += NT) hsin[i] = h_in[node0 * HID + i];
    __syncthreads();

    int c = t & 63, g = t >> 6;
    float scale = gam[c] * rsqrtf(var[c] + BN_EPS);
    float shift = bet[c] - mu[c] * scale;
    float cb = conv_b[c];

    float acc[4] = {0.f, 0.f, 0.f, 0.f};
    const float4* h0v = (const float4*)(hsin + (g * 4 + 0) * HID);
    const float4* h1v = (const float4*)(hsin + (g * 4 + 1) * HID);
    const float4* h2v = (const float4*)(hsin + (g * 4 + 2) * HID);
    const float4* h3v = (const float4*)(hsin + (g * 4 + 3) * HID);
#pragma unroll 4
    for (int k4 = 0; k4 < HID / 4; ++k4) {
        float4 hv[4];
        hv[0] = h0v[k4]; hv[1] = h1v[k4]; hv[2] = h2v[k4]; hv[3] = h3v[k4];
        const float* hf = (const float*)hv;
#pragma unroll
        for (int kk = 0; kk < 4; ++kk) {
            float wk = Ws[(k4 * 4 + kk) * 64 + c];
#pragma unroll
            for (int j = 0; j < 4; ++j) acc[j] += hf[j * 4 + kk] * wk;
        }
    }
#pragma unroll
    for (int j = 0; j < 4; ++j) {
        int node = node0 + g * 4 + j;
        float av = agg[node * HID + c];
        agg[node * HID + c] = 0.f;
        float v = fmaxf((av + acc[j] + cb) * scale + shift, 0.f);
        atomicAdd(&pooled[batch[node] * HID + c], v);
    }
}

// one block: 256 graphs; zero pooled after reading (restores state).
__global__ void clf_kernel(float* __restrict__ pooled,
                           const float* __restrict__ W,
                           const float* __restrict__ b,
                           float* __restrict__ out) {
    int gph = threadIdx.x;
    float acc0 = b[0], acc1 = b[1];
    float* pr = pooled + gph * HID;
#pragma unroll
    for (int k = 0; k < HID; ++k) {
        float p = pr[k];
        acc0 += p * W[k * 2 + 0];
        acc1 += p * W[k * 2 + 1];
    }
    out[gph * 2 + 0] = acc0;
    out[gph * 2 + 1] = acc1;
#pragma unroll
    for (int k = 0; k < HID; ++k) pr[k] = 0.f;
}

extern "C" void kernel_launch(void* const* d_in, const int* in_sizes, int n_in,
                              void* d_out, int out_size, void* d_ws, size_t ws_size,
                              hipStream_t stream) {
    const float* x         = (const float*)d_in[0];
    const int*   edge_index= (const int*)  d_in[1];
    const float* edge_attr = (const float*)d_in[2];
    const int*   batch     = (const int*)  d_in[3];
    const float* lin_in_W  = (const float*)d_in[4];
    const float* lin_in_b  = (const float*)d_in[5];
    const float* edge_W    = (const float*)d_in[6];   // [3,4,4096]
    const float* edge_b    = (const float*)d_in[7];   // [3,4096]
    const float* root_W    = (const float*)d_in[8];   // [3,64,64]
    const float* conv_b    = (const float*)d_in[9];   // [3,64]
    const float* bn_gamma  = (const float*)d_in[10];
    const float* bn_beta   = (const float*)d_in[11];
    const float* bn_mean   = (const float*)d_in[12];
    const float* bn_var    = (const float*)d_in[13];
    const float* clf_W     = (const float*)d_in[14];
    const float* clf_b     = (const float*)d_in[15];
    float* out = (float*)d_out;

    char* ws = (char*)d_ws;
    float*  hA     = (float*) (ws);                               // 2 MB
    float*  hB     = (float*) (ws + (size_t)2 * 1024 * 1024);     // 2 MB
    float*  agg    = (float*) (ws + (size_t)4 * 1024 * 1024);     // 2 MB
    float*  yb     = (float*) (ws + (size_t)6 * 1024 * 1024);     // 2 MB
    float*  pooled = (float*) (ws + (size_t)8 * 1024 * 1024);     // 64 KB
    float4* y4     = (float4*)(ws + (size_t)9 * 1024 * 1024);     // 8 MB

    k0_fused<<<N_NODES / NPB, NT, 0, stream>>>(
        x, lin_in_W, lin_in_b, edge_W, edge_b, hA, y4, yb, agg, pooled);

    edge_kernel<<<N_EDGES / 4, 256, 0, stream>>>(y4, yb, edge_attr, edge_index, agg);

    k_upd_ynet<<<N_NODES / NPB, NT, 0, stream>>>(
        hA, agg, root_W, conv_b, bn_gamma, bn_beta, bn_mean, bn_var,
        edge_W + (size_t)1 * EDGE_DIM * HID * HID, edge_b + (size_t)1 * HID * HID,
        hB, y4, yb);

    edge_kernel<<<N_EDGES / 4, 256, 0, stream>>>(y4, yb, edge_attr, edge_index, agg);

    k_upd_ynet<<<N_NODES / NPB, NT, 0, stream>>>(
        hB, agg, root_W + (size_t)1 * HID * HID, conv_b + (size_t)1 * HID,
        bn_gamma + HID, bn_beta + HID, bn_mean + HID, bn_var + HID,
        edge_W + (size_t)2 * EDGE_DIM * HID * HID, edge_b + (size_t)2 * HID * HID,
        hA, y4, yb);

    edge_kernel<<<N_EDGES / 4, 256, 0, stream>>>(y4, yb, edge_attr, edge_index, agg);

    k_upd_pool<<<N_NODES / NPB, NT, 0, stream>>>(
        hA, agg, root_W + (size_t)2 * HID * HID, conv_b + (size_t)2 * HID,
        bn_gamma + 2 * HID, bn_beta + 2 * HID, bn_mean + 2 * HID, bn_var + 2 * HID,
        batch, pooled);

    clf_kernel<<<1, 256, 0, stream>>>(pooled, clf_W, clf_b, out);
}